// Round 2
// baseline (155.656 us; speedup 1.0000x reference)
//
#include <hip/hip_runtime.h>

#define W 256
#define NA 180
#define SPLIT 4

__global__ __launch_bounds__(1024) void radon_kernel(
    const float* __restrict__ x, const int* __restrict__ index_p,
    float* __restrict__ out)
{
    const int a = blockIdx.x;        // angle 0..179
    const int n = blockIdx.y;        // batch
    const int tid = threadIdx.x;
    const int c = tid & (W - 1);     // column 0..255
    const int s = tid >> 8;          // r-chunk 0..3

    const int index = *index_p;
    const int seg[6] = {1, 26, 51, 77, 102, 128};
    const int t0 = seg[4 - index];
    const int t1 = seg[4 - index + 1];

    float sa, ca;
    sincosf((float)a * 0.017453292519943295f, &sa, &ca);

    const float xc = ((2.0f * (float)c + 1.0f) * (1.0f / (float)W)) - 1.0f;
    const float bx = 128.0f * ca * xc + 127.5f;
    const float by = -128.0f * sa * xc + 127.5f;

    const float* __restrict__ img = x + (size_t)n * W * W;

    const int r1lo = 128 - t1;
    const int r0lo = 128 - t0, r0hi = 127 + t0;
    const int total = 2 * t1;
    const int chunk = (total + SPLIT - 1) / SPLIT;
    const int rs = r1lo + s * chunk;
    const int re = min(rs + chunk, r1lo + total);

    float sum0 = 0.0f, sum1 = 0.0f;

    for (int r = rs; r < re; ++r) {
        const float rf = (float)r - 127.5f;
        const float ix = fmaf(sa, rf, bx);
        const float iy = fmaf(ca, rf, by);
        const float ix0f = floorf(ix);
        const float iy0f = floorf(iy);
        const float wx1 = ix - ix0f;
        const float wy1 = iy - iy0f;
        const int ix0 = (int)ix0f;
        const int iy0 = (int)iy0f;

        const int x0c = min(max(ix0, 0), W - 1);
        const int x1c = min(max(ix0 + 1, 0), W - 1);
        const int y0c = min(max(iy0, 0), W - 1);
        const int y1c = min(max(iy0 + 1, 0), W - 1);
        const bool vx0 = (ix0 >= 0) && (ix0 < W);
        const bool vx1 = (ix0 + 1 >= 0) && (ix0 + 1 < W);
        const bool vy0 = (iy0 >= 0) && (iy0 < W);
        const bool vy1 = (iy0 + 1 >= 0) && (iy0 + 1 < W);

        float v00 = img[y0c * W + x0c];
        float v01 = img[y0c * W + x1c];
        float v10 = img[y1c * W + x0c];
        float v11 = img[y1c * W + x1c];
        if (!(vy0 && vx0)) v00 = 0.0f;
        if (!(vy0 && vx1)) v01 = 0.0f;
        if (!(vy1 && vx0)) v10 = 0.0f;
        if (!(vy1 && vx1)) v11 = 0.0f;

        const float top = fmaf(wx1, v01 - v00, v00);
        const float bot = fmaf(wx1, v11 - v10, v10);
        const float val = fmaf(wy1, bot - top, top);

        sum1 += val;
        if (r >= r0lo && r <= r0hi) sum0 += val;
    }

    __shared__ float red0[SPLIT][W];
    __shared__ float red1[SPLIT][W];
    red0[s][c] = sum0;
    red1[s][c] = sum1;
    __syncthreads();

    if (s == 0) {
        const float acc0 = red0[0][c] + red0[1][c] + red0[2][c] + red0[3][c];
        const float acc1 = red1[0][c] + red1[1][c] + red1[2][c] + red1[3][c];
        out[(((size_t)n * 2 + 0) * W + c) * NA + a] = acc0 * (1.0f / (float)(2 * t0));
        out[(((size_t)n * 2 + 1) * W + c) * NA + a] = acc1 * (1.0f / (float)(2 * t1));
    }
}

extern "C" void kernel_launch(void* const* d_in, const int* in_sizes, int n_in,
                              void* d_out, int out_size, void* d_ws, size_t ws_size,
                              hipStream_t stream) {
    const float* x = (const float*)d_in[0];
    const int* index_p = (const int*)d_in[1];
    float* out = (float*)d_out;
    const int N = in_sizes[0] / (W * W); // 4
    dim3 grid(NA, N);
    radon_kernel<<<grid, 1024, 0, stream>>>(x, index_p, out);
}

// Round 3
// 59.373 us; speedup vs baseline: 2.6217x; 2.6217x over previous
//
#include <hip/hip_runtime.h>
#include <hip/hip_fp16.h>

#define W 256
#define NA 180
#define SPLIT 4

__global__ __launch_bounds__(1024) void radon_kernel(
    const float* __restrict__ x, const int* __restrict__ index_p,
    float* __restrict__ out)
{
    // 128 KiB: image as fp16, XOR-swizzled rows. half index = (r<<8) + (x ^ ((r&31)<<1))
    __shared__ __half simg[W * W];

    const int a = blockIdx.x;        // angle 0..179
    const int n = blockIdx.y;        // batch
    const int tid = threadIdx.x;
    const int c = tid & (W - 1);     // column 0..255
    const int s = tid >> 8;          // r-chunk 0..3

    const float* __restrict__ img = x + (size_t)n * W * W;

    // ---- stage image -> LDS as fp16, swizzled ----
    {
        const float4* img4 = (const float4*)img;
        #pragma unroll
        for (int k = 0; k < 16; ++k) {
            const int i4 = k * 1024 + tid;     // float4 index
            const float4 v = img4[i4];
            const int pix = i4 * 4;
            const int r = pix >> 8;
            const int xx = pix & (W - 1);
            const int swz = (r & 31) << 1;
            const int base = r << 8;
            simg[base + ((xx + 0) ^ swz)] = __float2half(v.x);
            simg[base + ((xx + 1) ^ swz)] = __float2half(v.y);
            simg[base + ((xx + 2) ^ swz)] = __float2half(v.z);
            simg[base + ((xx + 3) ^ swz)] = __float2half(v.w);
        }
    }
    __syncthreads();

    const int index = *index_p;
    const int seg[6] = {1, 26, 51, 77, 102, 128};
    const int t0 = seg[4 - index];
    const int t1 = seg[4 - index + 1];

    float sa, ca;
    sincosf((float)a * 0.017453292519943295f, &sa, &ca);

    const float xc = ((2.0f * (float)c + 1.0f) * (1.0f / (float)W)) - 1.0f;
    const float bx = 128.0f * ca * xc + 127.5f;
    const float by = -128.0f * sa * xc + 127.5f;

    const int r1lo = 128 - t1;
    const int r0lo = 128 - t0, r0hi = 127 + t0;
    const int total = 2 * t1;
    const int chunk = (total + SPLIT - 1) / SPLIT;
    const int rs = r1lo + s * chunk;
    const int re = min(rs + chunk, r1lo + total);

    float sum0 = 0.0f, sum1 = 0.0f;

    for (int r = rs; r < re; ++r) {
        const float rf = (float)r - 127.5f;
        const float ix = fmaf(sa, rf, bx);
        const float iy = fmaf(ca, rf, by);
        const float ix0f = floorf(ix);
        const float iy0f = floorf(iy);
        const float wx1 = ix - ix0f;
        const float wy1 = iy - iy0f;
        const int ix0 = (int)ix0f;
        const int iy0 = (int)iy0f;

        const int x0c = min(max(ix0, 0), W - 1);
        const int x1c = min(max(ix0 + 1, 0), W - 1);
        const int y0c = min(max(iy0, 0), W - 1);
        const int y1c = min(max(iy0 + 1, 0), W - 1);
        const bool vx0 = (ix0 >= 0) && (ix0 < W);
        const bool vx1 = (ix0 + 1 >= 0) && (ix0 + 1 < W);
        const bool vy0 = (iy0 >= 0) && (iy0 < W);
        const bool vy1 = (iy0 + 1 >= 0) && (iy0 + 1 < W);

        const int swz0 = (y0c & 31) << 1;
        const int swz1 = (y1c & 31) << 1;
        const int b0 = y0c << 8;
        const int b1 = y1c << 8;

        float v00 = __half2float(simg[b0 + (x0c ^ swz0)]);
        float v01 = __half2float(simg[b0 + (x1c ^ swz0)]);
        float v10 = __half2float(simg[b1 + (x0c ^ swz1)]);
        float v11 = __half2float(simg[b1 + (x1c ^ swz1)]);
        if (!(vy0 && vx0)) v00 = 0.0f;
        if (!(vy0 && vx1)) v01 = 0.0f;
        if (!(vy1 && vx0)) v10 = 0.0f;
        if (!(vy1 && vx1)) v11 = 0.0f;

        const float top = fmaf(wx1, v01 - v00, v00);
        const float bot = fmaf(wx1, v11 - v10, v10);
        const float val = fmaf(wy1, bot - top, top);

        sum1 += val;
        if (r >= r0lo && r <= r0hi) sum0 += val;
    }

    // ---- reduce partials; reuse simg as scratch (all reads of simg are done) ----
    __syncthreads();
    float* red = (float*)simg;                 // 2048 floats needed, 32768 available
    red[(0 * SPLIT + s) * W + c] = sum0;
    red[(1 * SPLIT + s) * W + c] = sum1;
    __syncthreads();

    if (s == 0) {
        const float acc0 = red[0 * W + c] + red[1 * W + c] + red[2 * W + c] + red[3 * W + c];
        const float* r1p = red + SPLIT * W;
        const float acc1 = r1p[0 * W + c] + r1p[1 * W + c] + r1p[2 * W + c] + r1p[3 * W + c];
        out[(((size_t)n * 2 + 0) * W + c) * NA + a] = acc0 * (1.0f / (float)(2 * t0));
        out[(((size_t)n * 2 + 1) * W + c) * NA + a] = acc1 * (1.0f / (float)(2 * t1));
    }
}

extern "C" void kernel_launch(void* const* d_in, const int* in_sizes, int n_in,
                              void* d_out, int out_size, void* d_ws, size_t ws_size,
                              hipStream_t stream) {
    const float* x = (const float*)d_in[0];
    const int* index_p = (const int*)d_in[1];
    float* out = (float*)d_out;
    const int N = in_sizes[0] / (W * W); // 4
    dim3 grid(NA, N);
    radon_kernel<<<grid, 1024, 0, stream>>>(x, index_p, out);
}

// Round 4
// 50.144 us; speedup vs baseline: 3.1042x; 1.1841x over previous
//
#include <hip/hip_runtime.h>
#include <hip/hip_fp16.h>

#define W 256
#define NA 180
#define SPLIT 4
#define STRIDE_H 288   // halfs per padded row (row bytes = 576)
#define ROWS 259       // rows 0..258 ; data in rows 1..256, cols 4..259
#define LDS_BYTES (ROWS * STRIDE_H * 2)   // 149184

__global__ __launch_bounds__(1024) void radon_kernel(
    const float* __restrict__ x, const int* __restrict__ index_p,
    float* __restrict__ out)
{
    __shared__ __half simg[ROWS * STRIDE_H];

    const int a = blockIdx.x;        // angle 0..179
    const int n = blockIdx.y;        // batch
    const int tid = threadIdx.x;
    const int c = tid & (W - 1);     // column 0..255
    const int s = tid >> 8;          // r-chunk 0..3

    const float* __restrict__ img = x + (size_t)n * W * W;

    // ---- zero-fill entire padded LDS image (guards) ----
    {
        uint4* p = (uint4*)simg;
        const int n16 = LDS_BYTES / 16;          // 9324
        for (int i = tid; i < n16; i += 1024) p[i] = make_uint4(0u, 0u, 0u, 0u);
    }
    __syncthreads();

    // ---- stage image -> LDS fp16, swizzled, via ds_write_b64 ----
    // half index h = x' ^ ((row&15)<<1); data col x' = pixel_x + 4, row = pixel_y + 1
    {
        const float4* img4 = (const float4*)img;
        #pragma unroll
        for (int k = 0; k < 16; ++k) {
            const int g = k * 1024 + tid;        // 0..16383 float4 groups
            const int row = (g >> 6) + 1;        // 1..256
            const int m = g & 63;
            const float4 v = img4[g];
            __half2 h01 = __floats2half2_rn(v.x, v.y);
            __half2 h23 = __floats2half2_rn(v.z, v.w);
            const int xp = 4 * m + 4;            // even, multiple of 4
            const int sw = row & 15;
            const int wbase = (xp >> 1) ^ sw;    // word index holding halfs (xp, xp+1)
            const int slot = wbase >> 1;         // aligned b64 slot
            uint2 payload;
            const unsigned u01 = *(const unsigned*)&h01;
            const unsigned u23 = *(const unsigned*)&h23;
            if (wbase & 1) { payload.x = u23; payload.y = u01; }
            else           { payload.x = u01; payload.y = u23; }
            *(uint2*)((char*)simg + row * 576 + slot * 8) = payload;
        }
    }
    __syncthreads();

    const int index = *index_p;
    const int seg[6] = {1, 26, 51, 77, 102, 128};
    const int t0 = seg[4 - index];
    const int t1 = seg[4 - index + 1];

    float sa, ca;
    sincosf((float)a * 0.017453292519943295f, &sa, &ca);

    const float xc = ((2.0f * (float)c + 1.0f) * (1.0f / (float)W)) - 1.0f;
    // biased bases: +4 in x, +1 in y (floor(v)+k == floor(v+k))
    const float bx = fmaf(128.0f * ca, xc, 127.5f + 4.0f);
    const float by = fmaf(-128.0f * sa, xc, 127.5f + 1.0f);

    const int r1lo = 128 - t1;
    const int r0lo = 128 - t0, r0hi = 127 + t0;
    const int total = 2 * t1;
    const int chunk = (total + SPLIT - 1) / SPLIT;
    const int rs = r1lo + s * chunk;
    const int re = min(rs + chunk, r1lo + total);

    float sum0 = 0.0f, sum1 = 0.0f;
    float rf = (float)rs - 127.5f;

    const char* S = (const char*)simg;

    for (int r = rs; r < re; ++r, rf += 1.0f) {
        float ix = fmaf(sa, rf, bx);             // biased coord in [.., ..]
        float iy = fmaf(ca, rf, by);
        ix = fminf(fmaxf(ix, 3.0f), 260.0f);     // clamp == per-tap zeroing via guards
        iy = fminf(fmaxf(iy, 0.0f), 257.0f);
        const float ix0f = floorf(ix);
        const float iy0f = floorf(iy);
        const float wx = ix - ix0f;
        const float wy = iy - iy0f;
        const int x0 = (int)ix0f;
        const int y0 = (int)iy0f;

        const int sw0 = (y0 & 15) << 1;
        const int sw1 = ((y0 + 1) & 15) << 1;
        const int b0 = y0 * 576;
        const int b1 = b0 + 576;

        const float v00 = __half2float(*(const __half*)(S + b0 + (((x0    ) ^ sw0) << 1)));
        const float v01 = __half2float(*(const __half*)(S + b0 + (((x0 + 1) ^ sw0) << 1)));
        const float v10 = __half2float(*(const __half*)(S + b1 + (((x0    ) ^ sw1) << 1)));
        const float v11 = __half2float(*(const __half*)(S + b1 + (((x0 + 1) ^ sw1) << 1)));

        const float top = fmaf(wx, v01 - v00, v00);
        const float bot = fmaf(wx, v11 - v10, v10);
        const float val = fmaf(wy, bot - top, top);

        sum1 += val;
        if (r >= r0lo && r <= r0hi) sum0 += val;
    }

    // ---- reduce partials; reuse simg as scratch ----
    __syncthreads();
    float* red = (float*)simg;                   // needs 8 KB of the 149 KB
    red[(0 * SPLIT + s) * W + c] = sum0;
    red[(1 * SPLIT + s) * W + c] = sum1;
    __syncthreads();

    if (s == 0) {
        const float acc0 = red[0 * W + c] + red[1 * W + c] + red[2 * W + c] + red[3 * W + c];
        const float* r1p = red + SPLIT * W;
        const float acc1 = r1p[0 * W + c] + r1p[1 * W + c] + r1p[2 * W + c] + r1p[3 * W + c];
        out[(((size_t)n * 2 + 0) * W + c) * NA + a] = acc0 * (1.0f / (float)(2 * t0));
        out[(((size_t)n * 2 + 1) * W + c) * NA + a] = acc1 * (1.0f / (float)(2 * t1));
    }
}

extern "C" void kernel_launch(void* const* d_in, const int* in_sizes, int n_in,
                              void* d_out, int out_size, void* d_ws, size_t ws_size,
                              hipStream_t stream) {
    const float* x = (const float*)d_in[0];
    const int* index_p = (const int*)d_in[1];
    float* out = (float*)d_out;
    const int N = in_sizes[0] / (W * W); // 4
    dim3 grid(NA, N);
    radon_kernel<<<grid, 1024, 0, stream>>>(x, index_p, out);
}